// Round 6
// baseline (443.931 us; speedup 1.0000x reference)
//
#include <hip/hip_runtime.h>
#include <hip/hip_bf16.h>

#define DD 256
#define KC 1024
#define BMA 64

typedef __attribute__((ext_vector_type(4))) float f32x4;
typedef __attribute__((ext_vector_type(8))) short bf16x8;

static __device__ __forceinline__ short f2bf(float f) {
    union { float f; unsigned u; } v; v.f = f;
    unsigned u = v.u;
    unsigned r = u + 0x7fffu + ((u >> 16) & 1u);
    return (short)(r >> 16);
}
static __device__ __forceinline__ float bf2f(short s) {
    union { unsigned u; float f; } v;
    v.u = ((unsigned)(unsigned short)s) << 16;
    return v.f;
}
static __device__ __forceinline__ unsigned pk2(float a, float b) {
    return (unsigned)(unsigned short)f2bf(a) |
           ((unsigned)(unsigned short)f2bf(b) << 16);
}

// ---------------------------------------------------------------------------
// prep: W fp32 [1024][256] -> wbf bf16 [1024][256], wtbf bf16 [256][1024],
//       wsq[k] = sum_d W[k][d]^2 / 256
// ---------------------------------------------------------------------------
__global__ void prep_kernel(const float* __restrict__ w, short* __restrict__ wbf,
                            short* __restrict__ wtbf, float* __restrict__ wsq) {
    const int cod = blockIdx.x;
    const int d   = threadIdx.x;           // 256 threads
    float v = w[cod * DD + d];
    short b = f2bf(v);
    wbf[cod * DD + d] = b;
    wtbf[d * KC + cod] = b;
    float s = v * v;
    #pragma unroll
    for (int m = 32; m >= 1; m >>= 1) s += __shfl_xor(s, m, 64);
    __shared__ float ps[4];
    const int wave = threadIdx.x >> 6, lane = threadIdx.x & 63;
    if (lane == 0) ps[wave] = s;
    __syncthreads();
    if (threadIdx.x == 0) {
        wsq[cod] = (ps[0] + ps[1] + ps[2] + ps[3]) * (1.0f / (float)DD);
    }
}

// ---------------------------------------------------------------------------
// score kernel: 64 rows/block, 512 thr (8 waves: h=w>>2 row-half, s=w&3 strip)
// x-tile (64x256 bf16) + W-tile (64 codes x 256, single buffer) in LDS with
// granule-XOR swizzle (g ^= row&7 on 16B granules) -> conflict-free ds_read.
// W-tile ct+1 loaded to regs during ct's compute (T14: issue-early).
// e kept packed bf16 in 64 VGPRs; qdist = bf2f(e)*inv stored at the end.
// LDS 65.3 KB -> 2 blocks/CU; VGPR <=128 -> 4 waves/SIMD.
// ---------------------------------------------------------------------------
__global__ __launch_bounds__(512, 4) void score_kernel(
    const float* __restrict__ x, const short* __restrict__ wbf,
    const float* __restrict__ wsq, float* __restrict__ qdist) {
    __shared__ short xs[BMA * DD];       // 32 KB
    __shared__ short wt[64 * DD];        // 32 KB
    __shared__ float red[4][BMA];        // 1 KB

    const int t = threadIdx.x;
    const int w = t >> 6, l = t & 63;
    const int lhi = l >> 4, llo = l & 15;
    const int h = w >> 2, s = w & 3;
    const long rowbase = (long)blockIdx.x * BMA;

    // ---- stage x tile (64x256 f32 -> bf16, swizzled granules) ----
    #pragma unroll
    for (int i = 0; i < 4; i++) {
        const int L = i * 512 + t, c = L >> 5, gl = L & 31, gp = gl ^ (c & 7);
        const float* xp = x + (rowbase + c) * DD + gl * 8;
        f32x4 v0 = *(const f32x4*)xp;
        f32x4 v1 = *(const f32x4*)(xp + 4);
        bf16x8 b;
        b[0] = f2bf(v0[0]); b[1] = f2bf(v0[1]); b[2] = f2bf(v0[2]); b[3] = f2bf(v0[3]);
        b[4] = f2bf(v1[0]); b[5] = f2bf(v1[1]); b[6] = f2bf(v1[2]); b[7] = f2bf(v1[3]);
        *(bf16x8*)((char*)xs + c * 512 + (gp << 4)) = b;
    }

    // ---- prologue: prefetch W tile 0 + wsq ----
    bf16x8 wpf[4];
    #pragma unroll
    for (int j = 0; j < 4; j++) {
        const int L = j * 512 + t, c = L >> 5, gl = L & 31;
        wpf[j] = *(const bf16x8*)(wbf + (size_t)c * DD + gl * 8);
    }
    float wsn = wsq[s * 16 + llo];
    __syncthreads();                     // xs ready

    float rs[2][4] = {{0.f,0.f,0.f,0.f},{0.f,0.f,0.f,0.f}};
    unsigned epk[16][2][2];

    const int cl = s * 16 + llo;         // this wave's code row in wt
    const int r0 = h * 32 + llo, r1 = r0 + 16;

    #pragma unroll
    for (int ct = 0; ct < 16; ct++) {
        // write staged W regs -> LDS (consumers of previous tile already
        // fenced by the barrier at the end of the previous iteration)
        #pragma unroll
        for (int j = 0; j < 4; j++) {
            const int L = j * 512 + t, c = L >> 5, gl = L & 31, gp = gl ^ (c & 7);
            *(bf16x8*)((char*)wt + c * 512 + (gp << 4)) = wpf[j];
        }
        const float ws = wsn;
        __syncthreads();                 // wt ready

        // issue next tile's loads (latency hidden under this tile's compute)
        if (ct < 15) {
            #pragma unroll
            for (int j = 0; j < 4; j++) {
                const int L = j * 512 + t, c = L >> 5, gl = L & 31;
                wpf[j] = *(const bf16x8*)(wbf + (size_t)((ct + 1) * 64 + c) * DD + gl * 8);
            }
            wsn = wsq[(ct + 1) * 64 + s * 16 + llo];
        }

        f32x4 acc0 = {0.f,0.f,0.f,0.f}, acc1 = {0.f,0.f,0.f,0.f};
        #pragma unroll
        for (int kk = 0; kk < 8; kk++) {
            const int g = lhi + kk * 4;
            bf16x8 bfr = *(const bf16x8*)((char*)wt + cl * 512 + ((g ^ (cl & 7)) << 4));
            bf16x8 a0  = *(const bf16x8*)((char*)xs + r0 * 512 + ((g ^ (r0 & 7)) << 4));
            bf16x8 a1  = *(const bf16x8*)((char*)xs + r1 * 512 + ((g ^ (r1 & 7)) << 4));
            acc0 = __builtin_amdgcn_mfma_f32_16x16x32_bf16(a0, bfr, acc0, 0, 0, 0);
            acc1 = __builtin_amdgcn_mfma_f32_16x16x32_bf16(a1, bfr, acc1, 0, 0, 0);
        }
        __syncthreads();                 // all wt reads done before next write

        float e0[4], e1[4];
        #pragma unroll
        for (int r = 0; r < 4; r++) {
            e0[r] = __expf(acc0[r] * (1.0f / 128.0f) - ws);
            e1[r] = __expf(acc1[r] * (1.0f / 128.0f) - ws);
            rs[0][r] += e0[r];
            rs[1][r] += e1[r];
        }
        epk[ct][0][0] = pk2(e0[0], e0[1]); epk[ct][0][1] = pk2(e0[2], e0[3]);
        epk[ct][1][0] = pk2(e1[0], e1[1]); epk[ct][1][1] = pk2(e1[2], e1[3]);
    }

    // ---- rowsum: reduce over llo lanes, then across the 4 s-waves ----
    #pragma unroll
    for (int m = 1; m <= 8; m <<= 1) {
        #pragma unroll
        for (int rg = 0; rg < 2; rg++)
            #pragma unroll
            for (int r = 0; r < 4; r++)
                rs[rg][r] += __shfl_xor(rs[rg][r], m, 64);
    }
    if (llo == 0) {
        #pragma unroll
        for (int rg = 0; rg < 2; rg++)
            #pragma unroll
            for (int r = 0; r < 4; r++)
                red[s][h * 32 + rg * 16 + lhi * 4 + r] = rs[rg][r];
    }
    __syncthreads();

    float inv[2][4];
    #pragma unroll
    for (int rg = 0; rg < 2; rg++)
        #pragma unroll
        for (int r = 0; r < 4; r++) {
            const int row = h * 32 + rg * 16 + lhi * 4 + r;
            inv[rg][r] = 1.0f / (red[0][row] + red[1][row] + red[2][row] + red[3][row]);
        }

    // ---- qdist stores ----
    float* qbase = qdist + rowbase * KC;
    #pragma unroll
    for (int ct = 0; ct < 16; ct++) {
        const int col = ct * 64 + s * 16 + llo;
        #pragma unroll
        for (int rg = 0; rg < 2; rg++)
            #pragma unroll
            for (int rr = 0; rr < 2; rr++) {
                const unsigned p = epk[ct][rg][rr];
                const int row = h * 32 + rg * 16 + lhi * 4 + rr * 2;
                qbase[(size_t)row * KC + col]       = bf2f((short)(p & 0xffff)) * inv[rg][rr * 2];
                qbase[(size_t)(row + 1) * KC + col] = bf2f((short)(p >> 16))    * inv[rg][rr * 2 + 1];
            }
    }
}

// ---------------------------------------------------------------------------
// pv kernel: quant = qdist @ W. No LDS, no barriers. 2048 blocks x 256 thr.
// Block owns 32 rows; wave w owns d-cols [w*64, w*64+64).
// A (qdist f32) loaded direct-to-frag + cvt; B (wtbf) direct-to-frag;
// both 1-step ping-pong prefetched. 16 waves/CU (VGPR ~100).
// ---------------------------------------------------------------------------
__global__ __launch_bounds__(256, 4) void pv_kernel(
    const float* __restrict__ qdist, const short* __restrict__ wtbf,
    float* __restrict__ quant) {
    const int t = threadIdx.x;
    const int w = t >> 6, l = t & 63;
    const int lhi = l >> 4, llo = l & 15;
    const long rowbase = (long)blockIdx.x * 32;
    const int dq = w * 64;

    f32x4 acc[2][4];
    #pragma unroll
    for (int rg = 0; rg < 2; rg++)
        #pragma unroll
        for (int dt = 0; dt < 4; dt++)
            acc[rg][dt] = (f32x4){0.f,0.f,0.f,0.f};

    const float* a0p = qdist + (rowbase + llo) * KC + lhi * 8;
    const float* a1p = a0p + (size_t)16 * KC;
    const short* bp  = wtbf + (size_t)(dq + llo) * KC + lhi * 8;

    // prologue prefetch (k-step 0)
    f32x4 qa0A = *(const f32x4*)a0p,       qa0B = *(const f32x4*)(a0p + 4);
    f32x4 qa1A = *(const f32x4*)a1p,       qa1B = *(const f32x4*)(a1p + 4);
    bf16x8 bpf[4];
    #pragma unroll
    for (int dt = 0; dt < 4; dt++) bpf[dt] = *(const bf16x8*)(bp + (size_t)dt * 16 * KC);

    for (int ks = 0; ks < 32; ks++) {
        // convert current A to bf16 frags
        bf16x8 af0, af1;
        af0[0]=f2bf(qa0A[0]); af0[1]=f2bf(qa0A[1]); af0[2]=f2bf(qa0A[2]); af0[3]=f2bf(qa0A[3]);
        af0[4]=f2bf(qa0B[0]); af0[5]=f2bf(qa0B[1]); af0[6]=f2bf(qa0B[2]); af0[7]=f2bf(qa0B[3]);
        af1[0]=f2bf(qa1A[0]); af1[1]=f2bf(qa1A[1]); af1[2]=f2bf(qa1A[2]); af1[3]=f2bf(qa1A[3]);
        af1[4]=f2bf(qa1B[0]); af1[5]=f2bf(qa1B[1]); af1[6]=f2bf(qa1B[2]); af1[7]=f2bf(qa1B[3]);
        bf16x8 bcur[4];
        #pragma unroll
        for (int dt = 0; dt < 4; dt++) bcur[dt] = bpf[dt];

        // issue next k-step loads (hidden under the 8 MFMAs below)
        if (ks < 31) {
            const int ko = (ks + 1) * 32;
            qa0A = *(const f32x4*)(a0p + ko);  qa0B = *(const f32x4*)(a0p + ko + 4);
            qa1A = *(const f32x4*)(a1p + ko);  qa1B = *(const f32x4*)(a1p + ko + 4);
            #pragma unroll
            for (int dt = 0; dt < 4; dt++)
                bpf[dt] = *(const bf16x8*)(bp + (size_t)dt * 16 * KC + ko);
        }

        #pragma unroll
        for (int dt = 0; dt < 4; dt++) {
            acc[0][dt] = __builtin_amdgcn_mfma_f32_16x16x32_bf16(af0, bcur[dt], acc[0][dt], 0, 0, 0);
            acc[1][dt] = __builtin_amdgcn_mfma_f32_16x16x32_bf16(af1, bcur[dt], acc[1][dt], 0, 0, 0);
        }
    }

    float* ob = quant + rowbase * DD + dq;
    #pragma unroll
    for (int rg = 0; rg < 2; rg++)
        #pragma unroll
        for (int dt = 0; dt < 4; dt++)
            #pragma unroll
            for (int r = 0; r < 4; r++)
                ob[(size_t)(rg * 16 + lhi * 4 + r) * DD + dt * 16 + llo] = acc[rg][dt][r];
}

// ---------------------------------------------------------------------------
extern "C" void kernel_launch(void* const* d_in, const int* in_sizes, int n_in,
                              void* d_out, int out_size, void* d_ws, size_t ws_size,
                              hipStream_t stream) {
    const float* x = (const float*)d_in[0];
    const float* w = (const float*)d_in[1];
    float* out = (float*)d_out;

    const int nrows = in_sizes[0] / DD;          // 65536
    float* quant = out;                          // [nrows][256]
    float* qdist = out + (size_t)nrows * DD;     // [nrows][1024]

    short* wbf  = (short*)d_ws;                  // 1024*256 bf16 = 512 KB
    short* wtbf = wbf + (size_t)KC * DD;         // 256*1024 bf16 = 512 KB
    float* wsq  = (float*)(wtbf + (size_t)DD * KC);  // 1024 fp32

    prep_kernel<<<KC, DD, 0, stream>>>(w, wbf, wtbf, wsq);
    score_kernel<<<nrows / BMA, 512, 0, stream>>>(x, wbf, wsq, qdist);
    pv_kernel<<<nrows / 32, 256, 0, stream>>>(qdist, wtbf, quant);
}

// Round 8
// 260.963 us; speedup vs baseline: 1.7011x; 1.7011x over previous
//
#include <hip/hip_runtime.h>
#include <hip/hip_bf16.h>

#define DD 256
#define KC 1024
#define NT 32     // 32 tiles of 32 codes

typedef __attribute__((ext_vector_type(4))) float f32x4;
typedef __attribute__((ext_vector_type(8))) short bf16x8;

static __device__ __forceinline__ short f2bf(float f) {
    union { float f; unsigned u; } v; v.f = f;
    unsigned u = v.u;
    unsigned r = u + 0x7fffu + ((u >> 16) & 1u);
    return (short)(r >> 16);
}
static __device__ __forceinline__ float bf2f(short s) {
    union { unsigned u; float f; } v;
    v.u = ((unsigned)(unsigned short)s) << 16;
    return v.f;
}

// ---------------------------------------------------------------------------
// prep: W fp32 [1024][256] -> wbf bf16 [1024][256], wtbf bf16 [256][1024],
//       wsq[k] = sum_d W[k][d]^2 / 256
// ---------------------------------------------------------------------------
__global__ void prep_kernel(const float* __restrict__ w, short* __restrict__ wbf,
                            short* __restrict__ wtbf, float* __restrict__ wsq) {
    const int cod = blockIdx.x;
    const int d   = threadIdx.x;           // 256 threads
    float v = w[cod * DD + d];
    short b = f2bf(v);
    wbf[cod * DD + d] = b;
    wtbf[d * KC + cod] = b;
    float s = v * v;
    #pragma unroll
    for (int m = 32; m >= 1; m >>= 1) s += __shfl_xor(s, m, 64);
    __shared__ float ps[4];
    const int wave = threadIdx.x >> 6, lane = threadIdx.x & 63;
    if (lane == 0) ps[wave] = s;
    __syncthreads();
    if (threadIdx.x == 0) {
        wsq[cod] = (ps[0] + ps[1] + ps[2] + ps[3]) * (1.0f / (float)DD);
    }
}

// ---------------------------------------------------------------------------
// Fused kernel, BM=64 rows/block, 512 thr (8 waves).
// Wave (rg = w>>1, cg = w&1) computes score rows [rg*16,+16) x codes [cg*16,+16)
// per 32-code tile; PV: wave w owns d-cols [w*32,+32).
// Pass 1: rowsums only. Pass 2: normalized scores -> et LDS -> vectorized
// qdist stores + PV MFMA from LDS (et + wtT), pipelined 1 tile behind,
// ONE barrier per tile. x fragments persist in registers for both passes.
// All W LDS tiles XOR-swizzled at 16B-granule level (conflict-free reads).
// NOTE: et_ holds NORMALIZED q (e*inv), so uacc IS quantized — no second
// inv multiply in the epilogue (R7 bug: double normalization).
// ---------------------------------------------------------------------------
__global__ __launch_bounds__(512, 4) void fused_kernel(
    const float* __restrict__ x, const short* __restrict__ wbf,
    const short* __restrict__ wtbf, const float* __restrict__ wsq,
    float* __restrict__ qdist, float* __restrict__ quant)
{
    __shared__ short wt_[2][32 * DD];     // 16 KB each: [code][256 d], swizzled
    __shared__ short wtT_[2][128 * 64];   // 16 KB each: [d>>1 superrow][64], swizzled
    __shared__ short et_[2][64 * 40];     // 5 KB each: q bf16 [row][32+8pad]
    __shared__ float red_[2][64];
    __shared__ float invs_[64];

    const int t   = threadIdx.x;
    const int w   = t >> 6, l = t & 63;
    const int lhi = l >> 4, llo = l & 15;
    const int rg  = w >> 1, cg = w & 1;
    const long rowbase = (long)blockIdx.x * 64;

    // staging thread identities
    const int sc  = t >> 4;              // wt: code 0..31
    const int sg0 = (t & 15) * 2;        // wt: first granule (even)
    const int sd  = t >> 1;              // wtT: d 0..255
    const int sg2 = (t & 1) * 2;         // wtT: granule pair in subrow
    const int ssr = sd >> 1;             // superrow
    const int shb = (sd & 1) * 4;

    bf16x8 wpf0, wpf1, tpf0, tpf1;
    float wscur, wsnext;

    // ---- issue wt tile0 loads ----
    { const short* p = wbf + (size_t)sc * DD + sg0 * 8;
      wpf0 = *(const bf16x8*)p; wpf1 = *(const bf16x8*)(p + 8); }

    // ---- x fragments (persist across both passes) ----
    bf16x8 xa[8];
    {
        const float* xr = x + (rowbase + rg * 16 + llo) * DD + lhi * 8;
        #pragma unroll
        for (int kk = 0; kk < 8; kk++) {
            f32x4 v0 = *(const f32x4*)(xr + kk * 32);
            f32x4 v1 = *(const f32x4*)(xr + kk * 32 + 4);
            bf16x8 b;
            b[0]=f2bf(v0[0]); b[1]=f2bf(v0[1]); b[2]=f2bf(v0[2]); b[3]=f2bf(v0[3]);
            b[4]=f2bf(v1[0]); b[5]=f2bf(v1[1]); b[6]=f2bf(v1[2]); b[7]=f2bf(v1[3]);
            xa[kk] = b;
        }
    }

    // ---- stage wt tile0; load wt tile1; wsq ----
    *(bf16x8*)((char*)wt_[0] + sc*512 + (((sg0    ) ^ (sc&7)) << 4)) = wpf0;
    *(bf16x8*)((char*)wt_[0] + sc*512 + (((sg0 + 1) ^ (sc&7)) << 4)) = wpf1;
    { const short* p = wbf + (size_t)(32 + sc) * DD + sg0 * 8;
      wpf0 = *(const bf16x8*)p; wpf1 = *(const bf16x8*)(p + 8); }
    wscur  = wsq[cg * 16 + llo];
    wsnext = wsq[32 + cg * 16 + llo];

    const int  mycode = cg * 16 + llo;
    const int  cswz   = mycode & 7;
    char* const wtb0  = (char*)wt_[0] + mycode * 512;
    char* const wtb1  = (char*)wt_[1] + mycode * 512;

    float rs[4] = {0.f, 0.f, 0.f, 0.f};

    // =================== PASS 1: rowsums ===================
    for (int i = 0; i < NT; i++) {
        __syncthreads();
        if (i < NT - 1) {               // stage tile i+1 -> wt[(i+1)&1]
            char* wb = (char*)wt_[(i + 1) & 1] + sc * 512;
            *(bf16x8*)(wb + (((sg0    ) ^ (sc&7)) << 4)) = wpf0;
            *(bf16x8*)(wb + (((sg0 + 1) ^ (sc&7)) << 4)) = wpf1;
        }
        if (i < NT - 2) {               // load tile i+2
            const short* p = wbf + (size_t)((i + 2) * 32 + sc) * DD + sg0 * 8;
            wpf0 = *(const bf16x8*)p; wpf1 = *(const bf16x8*)(p + 8);
        }
        char* wb2 = (i & 1) ? wtb1 : wtb0;
        f32x4 sacc = {0.f, 0.f, 0.f, 0.f};
        #pragma unroll
        for (int kk = 0; kk < 8; kk++) {
            bf16x8 bb = *(const bf16x8*)(wb2 + (((kk * 4 + lhi) ^ cswz) << 4));
            sacc = __builtin_amdgcn_mfma_f32_16x16x32_bf16(xa[kk], bb, sacc, 0, 0, 0);
        }
        #pragma unroll
        for (int r = 0; r < 4; r++)
            rs[r] += __expf(sacc[r] * (1.0f / 128.0f) - wscur);
        wscur = wsnext;
        if (i < NT - 2) wsnext = wsq[(i + 2) * 32 + cg * 16 + llo];
    }

    // ---- issue pass-2 tile0 loads early (cover under reduction) ----
    { const short* p = wbf + (size_t)sc * DD + sg0 * 8;
      wpf0 = *(const bf16x8*)p; wpf1 = *(const bf16x8*)(p + 8); }
    { const short* p = wtbf + (size_t)sd * KC + sg2 * 8;
      tpf0 = *(const bf16x8*)p; tpf1 = *(const bf16x8*)(p + 8); }

    // ---- rowsum reduce -> invs ----
    #pragma unroll
    for (int m = 1; m <= 8; m <<= 1)
        #pragma unroll
        for (int r = 0; r < 4; r++) rs[r] += __shfl_xor(rs[r], m, 64);
    if (llo == 0) {
        #pragma unroll
        for (int r = 0; r < 4; r++) red_[cg][rg * 16 + lhi * 4 + r] = rs[r];
    }
    __syncthreads();
    if (t < 64) invs_[t] = 1.0f / (red_[0][t] + red_[1][t]);
    __syncthreads();

    float inv4[4];
    #pragma unroll
    for (int r = 0; r < 4; r++) inv4[r] = invs_[rg * 16 + lhi * 4 + r];

    // stage pass-2 wt tile0 -> wt[0]; load wt tile1; wsq again
    *(bf16x8*)((char*)wt_[0] + sc*512 + (((sg0    ) ^ (sc&7)) << 4)) = wpf0;
    *(bf16x8*)((char*)wt_[0] + sc*512 + (((sg0 + 1) ^ (sc&7)) << 4)) = wpf1;
    { const short* p = wbf + (size_t)(32 + sc) * DD + sg0 * 8;
      wpf0 = *(const bf16x8*)p; wpf1 = *(const bf16x8*)(p + 8); }
    wscur  = wsq[cg * 16 + llo];
    wsnext = wsq[32 + cg * 16 + llo];

    f32x4 uacc[4][2];
    #pragma unroll
    for (int a = 0; a < 4; a++)
        #pragma unroll
        for (int b = 0; b < 2; b++) uacc[a][b] = (f32x4){0.f, 0.f, 0.f, 0.f};

    // =================== PASS 2: scores + qdist + PV ===================
    for (int i = 0; i < NT; i++) {
        __syncthreads();
        const int b = i & 1;
        if (i < NT - 1) {               // stage wt tile i+1 -> wt[b^1]
            char* wb = (char*)wt_[b ^ 1] + sc * 512;
            *(bf16x8*)(wb + (((sg0    ) ^ (sc&7)) << 4)) = wpf0;
            *(bf16x8*)(wb + (((sg0 + 1) ^ (sc&7)) << 4)) = wpf1;
        }
        if (i < NT - 2) {               // load wt tile i+2
            const short* p = wbf + (size_t)((i + 2) * 32 + sc) * DD + sg0 * 8;
            wpf0 = *(const bf16x8*)p; wpf1 = *(const bf16x8*)(p + 8);
        }
        {                               // stage wtT tile i -> wtT[b]
            char* tb = (char*)wtT_[b] + ssr * 128;
            *(bf16x8*)(tb + (((shb + sg2    ) ^ (ssr & 7)) << 4)) = tpf0;
            *(bf16x8*)(tb + (((shb + sg2 + 1) ^ (ssr & 7)) << 4)) = tpf1;
        }
        if (i < NT - 1) {               // load wtT tile i+1
            const short* p = wtbf + (size_t)sd * KC + (i + 1) * 32 + sg2 * 8;
            tpf0 = *(const bf16x8*)p; tpf1 = *(const bf16x8*)(p + 8);
        }
        if (i > 0) {                    // PV(i-1) + qdist(i-1) from buffers b^1
            const int pb = b ^ 1;
            bf16x8 aa[4];
            #pragma unroll
            for (int rowg = 0; rowg < 4; rowg++)
                aa[rowg] = *(const bf16x8*)((char*)et_[pb] + (rowg * 16 + llo) * 80 + lhi * 16);
            #pragma unroll
            for (int dg = 0; dg < 2; dg++) {
                const int d = w * 32 + dg * 16 + llo;
                bf16x8 bb = *(const bf16x8*)((char*)wtT_[pb] + (d >> 1) * 128 +
                               (((((d & 1) << 2) + lhi) ^ ((d >> 1) & 7)) << 4));
                #pragma unroll
                for (int rowg = 0; rowg < 4; rowg++)
                    uacc[rowg][dg] = __builtin_amdgcn_mfma_f32_16x16x32_bf16(aa[rowg], bb, uacc[rowg][dg], 0, 0, 0);
            }
            const int qrow = t >> 3, c4 = (t & 7) * 4;
            const char* ep = (const char*)et_[pb] + qrow * 80 + c4 * 2;
            unsigned u0 = *(const unsigned*)ep;
            unsigned u1 = *(const unsigned*)(ep + 4);
            f32x4 o;
            o[0] = bf2f((short)(u0 & 0xffff)); o[1] = bf2f((short)(u0 >> 16));
            o[2] = bf2f((short)(u1 & 0xffff)); o[3] = bf2f((short)(u1 >> 16));
            *(f32x4*)(qdist + (rowbase + qrow) * KC + (size_t)(i - 1) * 32 + c4) = o;
        }
        // score(i) -> et[b]  (normalized q)
        char* wb2 = b ? wtb1 : wtb0;
        f32x4 sacc = {0.f, 0.f, 0.f, 0.f};
        #pragma unroll
        for (int kk = 0; kk < 8; kk++) {
            bf16x8 bb = *(const bf16x8*)(wb2 + (((kk * 4 + lhi) ^ cswz) << 4));
            sacc = __builtin_amdgcn_mfma_f32_16x16x32_bf16(xa[kk], bb, sacc, 0, 0, 0);
        }
        char* eb = (char*)et_[b];
        #pragma unroll
        for (int r = 0; r < 4; r++) {
            float q = __expf(sacc[r] * (1.0f / 128.0f) - wscur) * inv4[r];
            *(short*)(eb + (rg * 16 + lhi * 4 + r) * 80 + mycode * 2) = f2bf(q);
        }
        wscur = wsnext;
        if (i < NT - 2) wsnext = wsq[(i + 2) * 32 + cg * 16 + llo];
    }

    // epilogue: PV(NT-1) + qdist(NT-1)
    __syncthreads();
    {
        const int pb = (NT - 1) & 1;
        bf16x8 aa[4];
        #pragma unroll
        for (int rowg = 0; rowg < 4; rowg++)
            aa[rowg] = *(const bf16x8*)((char*)et_[pb] + (rowg * 16 + llo) * 80 + lhi * 16);
        #pragma unroll
        for (int dg = 0; dg < 2; dg++) {
            const int d = w * 32 + dg * 16 + llo;
            bf16x8 bb = *(const bf16x8*)((char*)wtT_[pb] + (d >> 1) * 128 +
                           (((((d & 1) << 2) + lhi) ^ ((d >> 1) & 7)) << 4));
            #pragma unroll
            for (int rowg = 0; rowg < 4; rowg++)
                uacc[rowg][dg] = __builtin_amdgcn_mfma_f32_16x16x32_bf16(aa[rowg], bb, uacc[rowg][dg], 0, 0, 0);
        }
        const int qrow = t >> 3, c4 = (t & 7) * 4;
        const char* ep = (const char*)et_[pb] + qrow * 80 + c4 * 2;
        unsigned u0 = *(const unsigned*)ep;
        unsigned u1 = *(const unsigned*)(ep + 4);
        f32x4 o;
        o[0] = bf2f((short)(u0 & 0xffff)); o[1] = bf2f((short)(u0 >> 16));
        o[2] = bf2f((short)(u1 & 0xffff)); o[3] = bf2f((short)(u1 >> 16));
        *(f32x4*)(qdist + (rowbase + qrow) * KC + (size_t)(NT - 1) * 32 + c4) = o;
    }

    // quant = uacc (et_ already holds normalized q — no second inv multiply!)
    #pragma unroll
    for (int rowg = 0; rowg < 4; rowg++)
        #pragma unroll
        for (int dg = 0; dg < 2; dg++)
            #pragma unroll
            for (int r = 0; r < 4; r++) {
                const int row = rowg * 16 + lhi * 4 + r;
                quant[(rowbase + row) * DD + w * 32 + dg * 16 + llo] =
                    uacc[rowg][dg][r];
            }
}

// ---------------------------------------------------------------------------
extern "C" void kernel_launch(void* const* d_in, const int* in_sizes, int n_in,
                              void* d_out, int out_size, void* d_ws, size_t ws_size,
                              hipStream_t stream) {
    const float* x = (const float*)d_in[0];
    const float* w = (const float*)d_in[1];
    float* out = (float*)d_out;

    const int nrows = in_sizes[0] / DD;          // 65536
    float* quant = out;                          // [nrows][256]
    float* qdist = out + (size_t)nrows * DD;     // [nrows][1024]

    short* wbf  = (short*)d_ws;                  // 1024*256 bf16 = 512 KB
    short* wtbf = wbf + (size_t)KC * DD;         // 256*1024 bf16 = 512 KB
    float* wsq  = (float*)(wtbf + (size_t)DD * KC);  // 1024 fp32

    prep_kernel<<<KC, DD, 0, stream>>>(w, wbf, wtbf, wsq);
    fused_kernel<<<nrows / 64, 512, 0, stream>>>(x, wbf, wtbf, wsq, qdist, quant);
}

// Round 9
// 234.767 us; speedup vs baseline: 1.8909x; 1.1116x over previous
//
#include <hip/hip_runtime.h>
#include <hip/hip_bf16.h>

#define DD 256
#define KC 1024
#define NT 32     // 32 tiles of 32 codes

typedef __attribute__((ext_vector_type(4))) float f32x4;
typedef __attribute__((ext_vector_type(8))) short bf16x8;

// Raw barrier: LDS ordering only. Global stores + in-flight prefetch loads
// are NOT drained (T4). Data deps on loaded regs give counted vmcnt waits.
#define BAR() do { \
    asm volatile("s_waitcnt lgkmcnt(0)" ::: "memory"); \
    __builtin_amdgcn_s_barrier(); \
    __builtin_amdgcn_sched_barrier(0); \
} while (0)

static __device__ __forceinline__ short f2bf(float f) {
    union { float f; unsigned u; } v; v.f = f;
    unsigned u = v.u;
    unsigned r = u + 0x7fffu + ((u >> 16) & 1u);
    return (short)(r >> 16);
}
static __device__ __forceinline__ float bf2f(short s) {
    union { unsigned u; float f; } v;
    v.u = ((unsigned)(unsigned short)s) << 16;
    return v.f;
}

// ---------------------------------------------------------------------------
// prep: W fp32 [1024][256] -> wbf bf16 [1024][256], wtbf bf16 [256][1024],
//       wsq[k] = sum_d W[k][d]^2 / 256
// ---------------------------------------------------------------------------
__global__ void prep_kernel(const float* __restrict__ w, short* __restrict__ wbf,
                            short* __restrict__ wtbf, float* __restrict__ wsq) {
    const int cod = blockIdx.x;
    const int d   = threadIdx.x;           // 256 threads
    float v = w[cod * DD + d];
    short b = f2bf(v);
    wbf[cod * DD + d] = b;
    wtbf[d * KC + cod] = b;
    float s = v * v;
    #pragma unroll
    for (int m = 32; m >= 1; m >>= 1) s += __shfl_xor(s, m, 64);
    __shared__ float ps[4];
    const int wave = threadIdx.x >> 6, lane = threadIdx.x & 63;
    if (lane == 0) ps[wave] = s;
    __syncthreads();
    if (threadIdx.x == 0) {
        wsq[cod] = (ps[0] + ps[1] + ps[2] + ps[3]) * (1.0f / (float)DD);
    }
}

// ---------------------------------------------------------------------------
// Fused kernel, 64 rows/block, 512 thr (8 waves). R8 structure with:
//  - raw lgkm-only barriers in both tile loops (stores/prefetches in flight)
//  - PV computed transposed (mfma(bb,aa) -> D[d][row]) so quant stores are
//    f32x4 (fixes the 64 MB write amplification of scalar stores)
// ---------------------------------------------------------------------------
__global__ __launch_bounds__(512, 4) void fused_kernel(
    const float* __restrict__ x, const short* __restrict__ wbf,
    const short* __restrict__ wtbf, const float* __restrict__ wsq,
    float* __restrict__ qdist, float* __restrict__ quant)
{
    __shared__ short wt_[2][32 * DD];     // 16 KB each: [code][256 d], swizzled
    __shared__ short wtT_[2][128 * 64];   // 16 KB each: [d>>1 superrow][64], swizzled
    __shared__ short et_[2][64 * 40];     // 5 KB each: q bf16 [row][32+8pad]
    __shared__ float red_[2][64];
    __shared__ float invs_[64];

    const int t   = threadIdx.x;
    const int w   = t >> 6, l = t & 63;
    const int lhi = l >> 4, llo = l & 15;
    const int rg  = w >> 1, cg = w & 1;
    const long rowbase = (long)blockIdx.x * 64;

    // staging thread identities
    const int sc  = t >> 4;              // wt: code 0..31
    const int sg0 = (t & 15) * 2;        // wt: first granule (even)
    const int sd  = t >> 1;              // wtT: d 0..255
    const int sg2 = (t & 1) * 2;         // wtT: granule pair in subrow
    const int ssr = sd >> 1;             // superrow
    const int shb = (sd & 1) * 4;

    bf16x8 wpf0, wpf1, tpf0, tpf1;
    float wscur, wsnext;

    // ---- issue wt tile0 loads ----
    { const short* p = wbf + (size_t)sc * DD + sg0 * 8;
      wpf0 = *(const bf16x8*)p; wpf1 = *(const bf16x8*)(p + 8); }

    // ---- x fragments (persist across both passes) ----
    bf16x8 xa[8];
    {
        const float* xr = x + (rowbase + rg * 16 + llo) * DD + lhi * 8;
        #pragma unroll
        for (int kk = 0; kk < 8; kk++) {
            f32x4 v0 = *(const f32x4*)(xr + kk * 32);
            f32x4 v1 = *(const f32x4*)(xr + kk * 32 + 4);
            bf16x8 b;
            b[0]=f2bf(v0[0]); b[1]=f2bf(v0[1]); b[2]=f2bf(v0[2]); b[3]=f2bf(v0[3]);
            b[4]=f2bf(v1[0]); b[5]=f2bf(v1[1]); b[6]=f2bf(v1[2]); b[7]=f2bf(v1[3]);
            xa[kk] = b;
        }
    }

    // ---- stage wt tile0; load wt tile1; wsq ----
    *(bf16x8*)((char*)wt_[0] + sc*512 + (((sg0    ) ^ (sc&7)) << 4)) = wpf0;
    *(bf16x8*)((char*)wt_[0] + sc*512 + (((sg0 + 1) ^ (sc&7)) << 4)) = wpf1;
    { const short* p = wbf + (size_t)(32 + sc) * DD + sg0 * 8;
      wpf0 = *(const bf16x8*)p; wpf1 = *(const bf16x8*)(p + 8); }
    wscur  = wsq[cg * 16 + llo];
    wsnext = wsq[32 + cg * 16 + llo];

    const int  mycode = cg * 16 + llo;
    const int  cswz   = mycode & 7;
    char* const wtb0  = (char*)wt_[0] + mycode * 512;
    char* const wtb1  = (char*)wt_[1] + mycode * 512;

    float rs[4] = {0.f, 0.f, 0.f, 0.f};

    // =================== PASS 1: rowsums ===================
    for (int i = 0; i < NT; i++) {
        BAR();
        if (i < NT - 1) {               // stage tile i+1 -> wt[(i+1)&1]
            char* wb = (char*)wt_[(i + 1) & 1] + sc * 512;
            *(bf16x8*)(wb + (((sg0    ) ^ (sc&7)) << 4)) = wpf0;
            *(bf16x8*)(wb + (((sg0 + 1) ^ (sc&7)) << 4)) = wpf1;
        }
        if (i < NT - 2) {               // load tile i+2
            const short* p = wbf + (size_t)((i + 2) * 32 + sc) * DD + sg0 * 8;
            wpf0 = *(const bf16x8*)p; wpf1 = *(const bf16x8*)(p + 8);
        }
        char* wb2 = (i & 1) ? wtb1 : wtb0;
        f32x4 sacc = {0.f, 0.f, 0.f, 0.f};
        #pragma unroll
        for (int kk = 0; kk < 8; kk++) {
            bf16x8 bb = *(const bf16x8*)(wb2 + (((kk * 4 + lhi) ^ cswz) << 4));
            sacc = __builtin_amdgcn_mfma_f32_16x16x32_bf16(xa[kk], bb, sacc, 0, 0, 0);
        }
        #pragma unroll
        for (int r = 0; r < 4; r++)
            rs[r] += __expf(sacc[r] * (1.0f / 128.0f) - wscur);
        wscur = wsnext;
        if (i < NT - 2) wsnext = wsq[(i + 2) * 32 + cg * 16 + llo];
    }

    // ---- issue pass-2 tile0 loads early (cover under reduction) ----
    { const short* p = wbf + (size_t)sc * DD + sg0 * 8;
      wpf0 = *(const bf16x8*)p; wpf1 = *(const bf16x8*)(p + 8); }
    { const short* p = wtbf + (size_t)sd * KC + sg2 * 8;
      tpf0 = *(const bf16x8*)p; tpf1 = *(const bf16x8*)(p + 8); }

    // ---- rowsum reduce -> invs ----
    #pragma unroll
    for (int m = 1; m <= 8; m <<= 1)
        #pragma unroll
        for (int r = 0; r < 4; r++) rs[r] += __shfl_xor(rs[r], m, 64);
    if (llo == 0) {
        #pragma unroll
        for (int r = 0; r < 4; r++) red_[cg][rg * 16 + lhi * 4 + r] = rs[r];
    }
    __syncthreads();
    if (t < 64) invs_[t] = 1.0f / (red_[0][t] + red_[1][t]);
    __syncthreads();

    float inv4[4];
    #pragma unroll
    for (int r = 0; r < 4; r++) inv4[r] = invs_[rg * 16 + lhi * 4 + r];

    // stage pass-2 wt tile0 -> wt[0]; load wt tile1; wsq again
    *(bf16x8*)((char*)wt_[0] + sc*512 + (((sg0    ) ^ (sc&7)) << 4)) = wpf0;
    *(bf16x8*)((char*)wt_[0] + sc*512 + (((sg0 + 1) ^ (sc&7)) << 4)) = wpf1;
    { const short* p = wbf + (size_t)(32 + sc) * DD + sg0 * 8;
      wpf0 = *(const bf16x8*)p; wpf1 = *(const bf16x8*)(p + 8); }
    wscur  = wsq[cg * 16 + llo];
    wsnext = wsq[32 + cg * 16 + llo];

    f32x4 uacc[4][2];   // transposed PV: D[d-subtile][row-subtile]
    #pragma unroll
    for (int a = 0; a < 4; a++)
        #pragma unroll
        for (int b = 0; b < 2; b++) uacc[a][b] = (f32x4){0.f, 0.f, 0.f, 0.f};

    // =================== PASS 2: scores + qdist + PV ===================
    for (int i = 0; i < NT; i++) {
        BAR();
        const int b = i & 1;
        if (i < NT - 1) {               // stage wt tile i+1 -> wt[b^1]
            char* wb = (char*)wt_[b ^ 1] + sc * 512;
            *(bf16x8*)(wb + (((sg0    ) ^ (sc&7)) << 4)) = wpf0;
            *(bf16x8*)(wb + (((sg0 + 1) ^ (sc&7)) << 4)) = wpf1;
        }
        if (i < NT - 2) {               // load wt tile i+2
            const short* p = wbf + (size_t)((i + 2) * 32 + sc) * DD + sg0 * 8;
            wpf0 = *(const bf16x8*)p; wpf1 = *(const bf16x8*)(p + 8);
        }
        {                               // stage wtT tile i -> wtT[b]
            char* tb = (char*)wtT_[b] + ssr * 128;
            *(bf16x8*)(tb + (((shb + sg2    ) ^ (ssr & 7)) << 4)) = tpf0;
            *(bf16x8*)(tb + (((shb + sg2 + 1) ^ (ssr & 7)) << 4)) = tpf1;
        }
        if (i < NT - 1) {               // load wtT tile i+1
            const short* p = wtbf + (size_t)sd * KC + (i + 1) * 32 + sg2 * 8;
            tpf0 = *(const bf16x8*)p; tpf1 = *(const bf16x8*)(p + 8);
        }
        if (i > 0) {                    // PV(i-1) + qdist(i-1) from buffers b^1
            const int pb = b ^ 1;
            bf16x8 aa[4];
            #pragma unroll
            for (int rowg = 0; rowg < 4; rowg++)
                aa[rowg] = *(const bf16x8*)((char*)et_[pb] + (rowg * 16 + llo) * 80 + lhi * 16);
            #pragma unroll
            for (int dg = 0; dg < 2; dg++) {
                const int d = w * 32 + dg * 16 + llo;
                bf16x8 bb = *(const bf16x8*)((char*)wtT_[pb] + (d >> 1) * 128 +
                               (((((d & 1) << 2) + lhi) ^ ((d >> 1) & 7)) << 4));
                #pragma unroll
                for (int rowg = 0; rowg < 4; rowg++)
                    uacc[rowg][dg] = __builtin_amdgcn_mfma_f32_16x16x32_bf16(bb, aa[rowg], uacc[rowg][dg], 0, 0, 0);
            }
            const int qrow = t >> 3, c4 = (t & 7) * 4;
            const char* ep = (const char*)et_[pb] + qrow * 80 + c4 * 2;
            unsigned u0 = *(const unsigned*)ep;
            unsigned u1 = *(const unsigned*)(ep + 4);
            f32x4 o;
            o[0] = bf2f((short)(u0 & 0xffff)); o[1] = bf2f((short)(u0 >> 16));
            o[2] = bf2f((short)(u1 & 0xffff)); o[3] = bf2f((short)(u1 >> 16));
            *(f32x4*)(qdist + (rowbase + qrow) * KC + (size_t)(i - 1) * 32 + c4) = o;
        }
        // score(i) -> et[b]  (normalized q)
        char* wb2 = b ? wtb1 : wtb0;
        f32x4 sacc = {0.f, 0.f, 0.f, 0.f};
        #pragma unroll
        for (int kk = 0; kk < 8; kk++) {
            bf16x8 bb = *(const bf16x8*)(wb2 + (((kk * 4 + lhi) ^ cswz) << 4));
            sacc = __builtin_amdgcn_mfma_f32_16x16x32_bf16(xa[kk], bb, sacc, 0, 0, 0);
        }
        char* eb = (char*)et_[b];
        #pragma unroll
        for (int r = 0; r < 4; r++) {
            float q = __expf(sacc[r] * (1.0f / 128.0f) - wscur) * inv4[r];
            *(short*)(eb + (rg * 16 + lhi * 4 + r) * 80 + mycode * 2) = f2bf(q);
        }
        wscur = wsnext;
        if (i < NT - 2) wsnext = wsq[(i + 2) * 32 + cg * 16 + llo];
    }

    // epilogue: PV(NT-1) + qdist(NT-1)
    BAR();
    {
        const int pb = (NT - 1) & 1;
        bf16x8 aa[4];
        #pragma unroll
        for (int rowg = 0; rowg < 4; rowg++)
            aa[rowg] = *(const bf16x8*)((char*)et_[pb] + (rowg * 16 + llo) * 80 + lhi * 16);
        #pragma unroll
        for (int dg = 0; dg < 2; dg++) {
            const int d = w * 32 + dg * 16 + llo;
            bf16x8 bb = *(const bf16x8*)((char*)wtT_[pb] + (d >> 1) * 128 +
                           (((((d & 1) << 2) + lhi) ^ ((d >> 1) & 7)) << 4));
            #pragma unroll
            for (int rowg = 0; rowg < 4; rowg++)
                uacc[rowg][dg] = __builtin_amdgcn_mfma_f32_16x16x32_bf16(bb, aa[rowg], uacc[rowg][dg], 0, 0, 0);
        }
        const int qrow = t >> 3, c4 = (t & 7) * 4;
        const char* ep = (const char*)et_[pb] + qrow * 80 + c4 * 2;
        unsigned u0 = *(const unsigned*)ep;
        unsigned u1 = *(const unsigned*)(ep + 4);
        f32x4 o;
        o[0] = bf2f((short)(u0 & 0xffff)); o[1] = bf2f((short)(u0 >> 16));
        o[2] = bf2f((short)(u1 & 0xffff)); o[3] = bf2f((short)(u1 >> 16));
        *(f32x4*)(qdist + (rowbase + qrow) * KC + (size_t)(NT - 1) * 32 + c4) = o;
    }

    // quant stores: uacc[rowg][dg] = D[d = lhi*4+r][row = llo] -> f32x4 along d
    #pragma unroll
    for (int rowg = 0; rowg < 4; rowg++)
        #pragma unroll
        for (int dg = 0; dg < 2; dg++)
            *(f32x4*)(quant + (rowbase + rowg * 16 + llo) * DD + w * 32 + dg * 16 + lhi * 4)
                = uacc[rowg][dg];
}

// ---------------------------------------------------------------------------
extern "C" void kernel_launch(void* const* d_in, const int* in_sizes, int n_in,
                              void* d_out, int out_size, void* d_ws, size_t ws_size,
                              hipStream_t stream) {
    const float* x = (const float*)d_in[0];
    const float* w = (const float*)d_in[1];
    float* out = (float*)d_out;

    const int nrows = in_sizes[0] / DD;          // 65536
    float* quant = out;                          // [nrows][256]
    float* qdist = out + (size_t)nrows * DD;     // [nrows][1024]

    short* wbf  = (short*)d_ws;                  // 1024*256 bf16 = 512 KB
    short* wtbf = wbf + (size_t)KC * DD;         // 256*1024 bf16 = 512 KB
    float* wsq  = (float*)(wtbf + (size_t)DD * KC);  // 1024 fp32

    prep_kernel<<<KC, DD, 0, stream>>>(w, wbf, wtbf, wsq);
    fused_kernel<<<nrows / 64, 512, 0, stream>>>(x, wbf, wtbf, wsq, qdist, quant);
}

// Round 10
// 226.118 us; speedup vs baseline: 1.9633x; 1.0383x over previous
//
#include <hip/hip_runtime.h>
#include <hip/hip_bf16.h>

#define DD 256
#define KC 1024
#define NT 32     // 32 tiles of 32 codes

typedef __attribute__((ext_vector_type(4))) float f32x4;
typedef __attribute__((ext_vector_type(8))) short bf16x8;

// Raw barrier: LDS ordering only (T4). Global stores/prefetch stay in flight.
#define BAR() do { \
    asm volatile("s_waitcnt lgkmcnt(0)" ::: "memory"); \
    __builtin_amdgcn_s_barrier(); \
    __builtin_amdgcn_sched_barrier(0); \
} while (0)

static __device__ __forceinline__ short f2bf(float f) {
    union { float f; unsigned u; } v; v.f = f;
    unsigned u = v.u;
    unsigned r = u + 0x7fffu + ((u >> 16) & 1u);
    return (short)(r >> 16);
}
static __device__ __forceinline__ float bf2f(short s) {
    union { unsigned u; float f; } v;
    v.u = ((unsigned)(unsigned short)s) << 16;
    return v.f;
}
static __device__ __forceinline__ unsigned pk2(float a, float b) {
    return (unsigned)(unsigned short)f2bf(a) |
           ((unsigned)(unsigned short)f2bf(b) << 16);
}

// ---------------------------------------------------------------------------
// prep: W fp32 [1024][256] -> wbf bf16 [1024][256], wtbf bf16 [256][1024],
//       wsq[k] = sum_d W[k][d]^2 / 256
// ---------------------------------------------------------------------------
__global__ void prep_kernel(const float* __restrict__ w, short* __restrict__ wbf,
                            short* __restrict__ wtbf, float* __restrict__ wsq) {
    const int cod = blockIdx.x;
    const int d   = threadIdx.x;           // 256 threads
    float v = w[cod * DD + d];
    short b = f2bf(v);
    wbf[cod * DD + d] = b;
    wtbf[d * KC + cod] = b;
    float s = v * v;
    #pragma unroll
    for (int m = 32; m >= 1; m >>= 1) s += __shfl_xor(s, m, 64);
    __shared__ float ps[4];
    const int wave = threadIdx.x >> 6, lane = threadIdx.x & 63;
    if (lane == 0) ps[wave] = s;
    __syncthreads();
    if (threadIdx.x == 0) {
        wsq[cod] = (ps[0] + ps[1] + ps[2] + ps[3]) * (1.0f / (float)DD);
    }
}

// ---------------------------------------------------------------------------
// Fused kernel, 64 rows/block, 512 thr (8 waves).
// PASS 1: scores via wt-LDS dbuf pipeline; e kept PACKED-BF16 IN REGISTERS
//         (epk[32][2] u32) — no pass-2 score recompute (MFMA 768->512/wave).
// PASS 2: PV only — et (stride 72B, conflict-free) + wtT dbuf; qdist stored
//         directly from e-registers; 1 raw barrier per tile.
// LDS-pipe traffic ~ -45% vs R9 (the R9 bottleneck: LDS pipe ~80% busy).
// ---------------------------------------------------------------------------
__global__ __launch_bounds__(512, 4) void fused_kernel(
    const float* __restrict__ x, const short* __restrict__ wbf,
    const short* __restrict__ wtbf, const float* __restrict__ wsq,
    float* __restrict__ qdist, float* __restrict__ quant)
{
    __shared__ short wt_[2][32 * DD];     // 16 KB each: [code][256 d], swizzled
    __shared__ short wtT_[2][128 * 64];   // 16 KB each: superrow layout, swizzled
    __shared__ short et_[2][64 * 36];     // 4.6 KB each: q bf16 [row][32+4pad]
    __shared__ float red_[2][64];
    __shared__ float invs_[64];

    const int t   = threadIdx.x;
    const int w   = t >> 6, l = t & 63;
    const int lhi = l >> 4, llo = l & 15;
    const int rg  = w >> 1, cg = w & 1;
    const long rowbase = (long)blockIdx.x * 64;

    // staging thread identities
    const int sc  = t >> 4;              // wt: code 0..31
    const int sg0 = (t & 15) * 2;        // wt: first granule (even)
    const int sd  = t >> 1;              // wtT: d 0..255
    const int sg2 = (t & 1) * 2;         // wtT: granule pair in subrow
    const int ssr = sd >> 1;             // superrow
    const int shb = (sd & 1) * 4;

    bf16x8 wpf0, wpf1;
    float wscur, wsnext;

    // ---- issue wt tile0 loads ----
    { const short* p = wbf + (size_t)sc * DD + sg0 * 8;
      wpf0 = *(const bf16x8*)p; wpf1 = *(const bf16x8*)(p + 8); }

    // ---- x fragments (registers, pass-1 only) ----
    bf16x8 xa[8];
    {
        const float* xr = x + (rowbase + rg * 16 + llo) * DD + lhi * 8;
        #pragma unroll
        for (int kk = 0; kk < 8; kk++) {
            f32x4 v0 = *(const f32x4*)(xr + kk * 32);
            f32x4 v1 = *(const f32x4*)(xr + kk * 32 + 4);
            bf16x8 b;
            b[0]=f2bf(v0[0]); b[1]=f2bf(v0[1]); b[2]=f2bf(v0[2]); b[3]=f2bf(v0[3]);
            b[4]=f2bf(v1[0]); b[5]=f2bf(v1[1]); b[6]=f2bf(v1[2]); b[7]=f2bf(v1[3]);
            xa[kk] = b;
        }
    }

    // ---- stage wt tile0; load wt tile1; wsq ----
    *(bf16x8*)((char*)wt_[0] + sc*512 + (((sg0    ) ^ (sc&7)) << 4)) = wpf0;
    *(bf16x8*)((char*)wt_[0] + sc*512 + (((sg0 + 1) ^ (sc&7)) << 4)) = wpf1;
    { const short* p = wbf + (size_t)(32 + sc) * DD + sg0 * 8;
      wpf0 = *(const bf16x8*)p; wpf1 = *(const bf16x8*)(p + 8); }
    wscur  = wsq[cg * 16 + llo];
    wsnext = wsq[32 + cg * 16 + llo];

    const int  mycode = cg * 16 + llo;
    const int  cswz   = mycode & 7;
    char* const wtb0  = (char*)wt_[0] + mycode * 512;
    char* const wtb1  = (char*)wt_[1] + mycode * 512;

    float rs[4] = {0.f, 0.f, 0.f, 0.f};
    unsigned epk[NT][2];                 // packed bf16 e, fully unrolled access

    // =================== PASS 1: scores -> e in registers ===================
    #pragma unroll
    for (int i = 0; i < NT; i++) {
        BAR();
        if (i < NT - 1) {               // stage tile i+1 -> wt[(i+1)&1]
            char* wb = (char*)wt_[(i + 1) & 1] + sc * 512;
            *(bf16x8*)(wb + (((sg0    ) ^ (sc&7)) << 4)) = wpf0;
            *(bf16x8*)(wb + (((sg0 + 1) ^ (sc&7)) << 4)) = wpf1;
        }
        if (i < NT - 2) {               // load tile i+2
            const short* p = wbf + (size_t)((i + 2) * 32 + sc) * DD + sg0 * 8;
            wpf0 = *(const bf16x8*)p; wpf1 = *(const bf16x8*)(p + 8);
        }
        char* wb2 = (i & 1) ? wtb1 : wtb0;
        f32x4 sacc = {0.f, 0.f, 0.f, 0.f};
        #pragma unroll
        for (int kk = 0; kk < 8; kk++) {
            bf16x8 bb = *(const bf16x8*)(wb2 + (((kk * 4 + lhi) ^ cswz) << 4));
            sacc = __builtin_amdgcn_mfma_f32_16x16x32_bf16(xa[kk], bb, sacc, 0, 0, 0);
        }
        float e0 = __expf(sacc[0] * (1.0f / 128.0f) - wscur);
        float e1 = __expf(sacc[1] * (1.0f / 128.0f) - wscur);
        float e2 = __expf(sacc[2] * (1.0f / 128.0f) - wscur);
        float e3 = __expf(sacc[3] * (1.0f / 128.0f) - wscur);
        rs[0] += e0; rs[1] += e1; rs[2] += e2; rs[3] += e3;
        epk[i][0] = pk2(e0, e1);
        epk[i][1] = pk2(e2, e3);
        wscur = wsnext;
        if (i < NT - 2) wsnext = wsq[(i + 2) * 32 + cg * 16 + llo];
    }

    // ---- issue wtT tile0 loads early (cover under reduction) ----
    bf16x8 tpf0, tpf1;
    { const short* p = wtbf + (size_t)sd * KC + sg2 * 8;
      tpf0 = *(const bf16x8*)p; tpf1 = *(const bf16x8*)(p + 8); }

    // ---- rowsum reduce -> invs ----
    #pragma unroll
    for (int m = 1; m <= 8; m <<= 1)
        #pragma unroll
        for (int r = 0; r < 4; r++) rs[r] += __shfl_xor(rs[r], m, 64);
    if (llo == 0) {
        #pragma unroll
        for (int r = 0; r < 4; r++) red_[cg][rg * 16 + lhi * 4 + r] = rs[r];
    }
    __syncthreads();
    if (t < 64) invs_[t] = 1.0f / (red_[0][t] + red_[1][t]);
    __syncthreads();

    float inv4[4];
    #pragma unroll
    for (int r = 0; r < 4; r++) inv4[r] = invs_[rg * 16 + lhi * 4 + r];

    f32x4 uacc[4][2];   // transposed PV: D[d-subtile][row-subtile]
    #pragma unroll
    for (int a = 0; a < 4; a++)
        #pragma unroll
        for (int b = 0; b < 2; b++) uacc[a][b] = (f32x4){0.f, 0.f, 0.f, 0.f};

    float* qbase = qdist + rowbase * KC;
    const int myrow0 = rg * 16 + lhi * 4;

    // =================== PASS 2: PV + outputs (1 barrier/tile) ==============
    #pragma unroll
    for (int i = 0; i < NT; i++) {
        const int b = i & 1;
        // q values for tile i (from registers)
        float q0 = bf2f((short)(epk[i][0] & 0xffff)) * inv4[0];
        float q1 = bf2f((short)(epk[i][0] >> 16))    * inv4[1];
        float q2 = bf2f((short)(epk[i][1] & 0xffff)) * inv4[2];
        float q3 = bf2f((short)(epk[i][1] >> 16))    * inv4[3];
        // et write (stride 36 shorts = 72 B: conflict-free)
        et_[b][(myrow0 + 0) * 36 + mycode] = f2bf(q0);
        et_[b][(myrow0 + 1) * 36 + mycode] = f2bf(q1);
        et_[b][(myrow0 + 2) * 36 + mycode] = f2bf(q2);
        et_[b][(myrow0 + 3) * 36 + mycode] = f2bf(q3);
        // qdist stores (straight from registers, no LDS)
        {
            const int col = i * 32 + mycode;
            qbase[(size_t)(myrow0 + 0) * KC + col] = q0;
            qbase[(size_t)(myrow0 + 1) * KC + col] = q1;
            qbase[(size_t)(myrow0 + 2) * KC + col] = q2;
            qbase[(size_t)(myrow0 + 3) * KC + col] = q3;
        }
        // stage wtT tile i -> wtT[b]
        {
            char* tb = (char*)wtT_[b] + ssr * 128;
            *(bf16x8*)(tb + (((shb + sg2    ) ^ (ssr & 7)) << 4)) = tpf0;
            *(bf16x8*)(tb + (((shb + sg2 + 1) ^ (ssr & 7)) << 4)) = tpf1;
        }
        if (i < NT - 1) {               // load wtT tile i+1
            const short* p = wtbf + (size_t)sd * KC + (i + 1) * 32 + sg2 * 8;
            tpf0 = *(const bf16x8*)p; tpf1 = *(const bf16x8*)(p + 8);
        }
        BAR();
        // PV from et_[b] + wtT_[b]
        bf16x8 bb0, bb1;
        {
            const int d0 = w * 32 + llo;
            bb0 = *(const bf16x8*)((char*)wtT_[b] + (d0 >> 1) * 128 +
                    (((((d0 & 1) << 2) + lhi) ^ ((d0 >> 1) & 7)) << 4));
            const int d1 = w * 32 + 16 + llo;
            bb1 = *(const bf16x8*)((char*)wtT_[b] + (d1 >> 1) * 128 +
                    (((((d1 & 1) << 2) + lhi) ^ ((d1 >> 1) & 7)) << 4));
        }
        #pragma unroll
        for (int rowg = 0; rowg < 4; rowg++) {
            bf16x8 aa = *(const bf16x8*)((char*)et_[b] + (rowg * 16 + llo) * 72 + lhi * 16);
            uacc[rowg][0] = __builtin_amdgcn_mfma_f32_16x16x32_bf16(bb0, aa, uacc[rowg][0], 0, 0, 0);
            uacc[rowg][1] = __builtin_amdgcn_mfma_f32_16x16x32_bf16(bb1, aa, uacc[rowg][1], 0, 0, 0);
        }
    }

    // quant stores: uacc[rowg][dg] = D[d][row] -> f32x4 along d (R9-verified map)
    #pragma unroll
    for (int rowg = 0; rowg < 4; rowg++)
        #pragma unroll
        for (int dg = 0; dg < 2; dg++)
            *(f32x4*)(quant + (rowbase + rowg * 16 + llo) * DD + w * 32 + dg * 16 + lhi * 4)
                = uacc[rowg][dg];
}

// ---------------------------------------------------------------------------
extern "C" void kernel_launch(void* const* d_in, const int* in_sizes, int n_in,
                              void* d_out, int out_size, void* d_ws, size_t ws_size,
                              hipStream_t stream) {
    const float* x = (const float*)d_in[0];
    const float* w = (const float*)d_in[1];
    float* out = (float*)d_out;

    const int nrows = in_sizes[0] / DD;          // 65536
    float* quant = out;                          // [nrows][256]
    float* qdist = out + (size_t)nrows * DD;     // [nrows][1024]

    short* wbf  = (short*)d_ws;                  // 1024*256 bf16 = 512 KB
    short* wtbf = wbf + (size_t)KC * DD;         // 256*1024 bf16 = 512 KB
    float* wsq  = (float*)(wtbf + (size_t)DD * KC);  // 1024 fp32

    prep_kernel<<<KC, DD, 0, stream>>>(w, wbf, wtbf, wsq);
    fused_kernel<<<nrows / 64, 512, 0, stream>>>(x, wbf, wtbf, wsq, qdist, quant);
}